// Round 1
// baseline (123275.574 us; speedup 1.0000x reference)
//
#include <hip/hip_runtime.h>

#define BB 128
#define TT 1024
#define II 256
#define HH 512
#define KK 768   // I+H

#define NWG 128
#define NTHR 256

// Monotonic global barrier: each WG's thread0 adds 1, spins until cnt >= target.
// Sound because cnt can only reach g*NWG after all NWG workgroups performed
// their g-th increment. Counter is reset by hipMemsetAsync every launch.
__device__ __forceinline__ void gbar(unsigned* cnt, unsigned target) {
    __syncthreads();
    if (threadIdx.x == 0) {
        __hip_atomic_fetch_add(cnt, 1u, __ATOMIC_ACQ_REL, __HIP_MEMORY_SCOPE_AGENT);
        while (__hip_atomic_load(cnt, __ATOMIC_ACQUIRE, __HIP_MEMORY_SCOPE_AGENT) < target) {
            __builtin_amdgcn_s_sleep(1);
        }
    }
    __syncthreads();
}

__global__ __launch_bounds__(NTHR) void gru_kernel(
    const float* __restrict__ x,
    const float* __restrict__ Wz, const float* __restrict__ bz,
    const float* __restrict__ Wr, const float* __restrict__ br,
    const float* __restrict__ Wh, const float* __restrict__ bh,
    float* __restrict__ out,
    float* __restrict__ hbuf,   // [2][B][H] double-buffered hidden state
    float* __restrict__ zbuf,   // [B][H]
    float* __restrict__ rbuf,   // [B][H]
    unsigned* __restrict__ bar)
{
    const int wg  = blockIdx.x;
    const int tid = threadIdx.x;

    __shared__ float As[32][17];   // comb tile  [32 rows][16 k] (+1 pad)
    __shared__ float Bs[16][34];   // weight tile [16 k][32 n]  (+2 pad, float2-aligned)

    const int mt = wg >> 5;        // 0..3   (M tile of 32 rows)
    const int nt = wg & 31;        // 0..31  (N tile)
    const int tx = tid & 15;       // 0..15
    const int ty = tid >> 4;       // 0..15

    unsigned nbar = 0;

    for (int t = 0; t < TT; ++t) {
        const float* hprev = hbuf + (size_t)(t & 1) * (BB * HH);
        float*       hnext = hbuf + (size_t)((t & 1) ^ 1) * (BB * HH);

        // ---------------- phase 1: [z|r] = sigmoid(comb @ [Wz|Wr] + [bz|br]) ----------------
        {
            const int m0 = mt * 32;
            const int n0 = nt * 32;           // 0..1023, tiles never straddle the 512 boundary
            float acc00 = 0.f, acc01 = 0.f, acc10 = 0.f, acc11 = 0.f;

            for (int kb = 0; kb < KK; kb += 16) {
                // stage comb tile: comb[m][k] = k<I ? x[m,t,k] : hprev[m][k-I]
                for (int e = tid; e < 32 * 16; e += NTHR) {
                    const int r = e >> 4, c = e & 15;
                    const int k = kb + c, m = m0 + r;
                    float v;
                    if (k < II) v = x[(size_t)m * (TT * II) + (size_t)t * II + k];
                    else        v = hprev[m * HH + (k - II)];
                    As[r][c] = v;
                }
                // stage weight tile: W[k][n], n<H -> Wz, else Wr
                for (int e = tid; e < 16 * 32; e += NTHR) {
                    const int r = e >> 5, c = e & 31;
                    const int k = kb + r, n = n0 + c;
                    Bs[r][c] = (n < HH) ? Wz[k * HH + n] : Wr[k * HH + (n - HH)];
                }
                __syncthreads();
                #pragma unroll
                for (int kk = 0; kk < 16; ++kk) {
                    const float a0 = As[ty * 2 + 0][kk];
                    const float a1 = As[ty * 2 + 1][kk];
                    const float b0 = Bs[kk][tx * 2 + 0];
                    const float b1 = Bs[kk][tx * 2 + 1];
                    acc00 += a0 * b0; acc01 += a0 * b1;
                    acc10 += a1 * b0; acc11 += a1 * b1;
                }
                __syncthreads();
            }

            #pragma unroll
            for (int i = 0; i < 2; ++i) {
                const int m = m0 + ty * 2 + i;
                #pragma unroll
                for (int j = 0; j < 2; ++j) {
                    const int n = n0 + tx * 2 + j;
                    float acc = i ? (j ? acc11 : acc10) : (j ? acc01 : acc00);
                    const float bias = (n < HH) ? bz[n] : br[n - HH];
                    const float s = 1.0f / (1.0f + expf(-(acc + bias)));
                    if (n < HH) zbuf[m * HH + n] = s;
                    else        rbuf[m * HH + (n - HH)] = s;
                }
            }
        }
        ++nbar; gbar(bar, nbar * NWG);

        // ---------------- phase 2: hc = tanh(comb2 @ Wh + bh); h = (1-z)h + z*hc ----------------
        {
            const int m0 = mt * 32;
            const int n0 = nt * 16;           // 32 N-tiles of 16
            float acc0 = 0.f, acc1 = 0.f;

            for (int kb = 0; kb < KK; kb += 16) {
                // stage comb2 tile: k<I ? x[m,t,k] : r[m][k-I]*h[m][k-I]
                for (int e = tid; e < 32 * 16; e += NTHR) {
                    const int r = e >> 4, c = e & 15;
                    const int k = kb + c, m = m0 + r;
                    float v;
                    if (k < II) v = x[(size_t)m * (TT * II) + (size_t)t * II + k];
                    else {
                        const int kh = k - II;
                        v = rbuf[m * HH + kh] * hprev[m * HH + kh];
                    }
                    As[r][c] = v;
                }
                // stage Wh tile 16x16 (one element per thread)
                {
                    const int r = tid >> 4, c = tid & 15;
                    Bs[r][c] = Wh[(kb + r) * HH + (n0 + c)];
                }
                __syncthreads();
                #pragma unroll
                for (int kk = 0; kk < 16; ++kk) {
                    const float b0 = Bs[kk][tx];
                    acc0 += As[ty * 2 + 0][kk] * b0;
                    acc1 += As[ty * 2 + 1][kk] * b0;
                }
                __syncthreads();
            }

            #pragma unroll
            for (int i = 0; i < 2; ++i) {
                const int m = m0 + ty * 2 + i;
                const int n = n0 + tx;
                const float acc = i ? acc1 : acc0;
                const float hc = tanhf(acc + bh[n]);
                const float z  = zbuf[m * HH + n];
                const float ho = hprev[m * HH + n];
                const float hn = (1.0f - z) * ho + z * hc;
                hnext[m * HH + n] = hn;
                out[(size_t)m * (TT * HH) + (size_t)t * HH + n] = hn;
            }
        }
        ++nbar; gbar(bar, nbar * NWG);
    }
}

extern "C" void kernel_launch(void* const* d_in, const int* in_sizes, int n_in,
                              void* d_out, int out_size, void* d_ws, size_t ws_size,
                              hipStream_t stream) {
    const float* x  = (const float*)d_in[0];
    const float* Wz = (const float*)d_in[1];
    const float* bz = (const float*)d_in[2];
    const float* Wr = (const float*)d_in[3];
    const float* br = (const float*)d_in[4];
    const float* Wh = (const float*)d_in[5];
    const float* bh = (const float*)d_in[6];
    float* out = (float*)d_out;

    float* ws_f  = (float*)d_ws;
    float* hbuf  = ws_f;                        // 2*B*H floats
    float* zbuf  = hbuf + 2 * BB * HH;          // B*H
    float* rbuf  = zbuf + BB * HH;              // B*H
    unsigned* bar = (unsigned*)(rbuf + BB * HH);

    const size_t need = (size_t)(4 * BB * HH) * sizeof(float) + 64;
    if (ws_size < need) return;  // fail loudly (output stays poisoned)

    // zero h0 (both buffers) and the barrier counter each call -> deterministic replays
    hipMemsetAsync(hbuf, 0, (size_t)(2 * BB * HH) * sizeof(float), stream);
    hipMemsetAsync(bar, 0, 2 * sizeof(unsigned), stream);

    gru_kernel<<<NWG, NTHR, 0, stream>>>(x, Wz, bz, Wr, br, Wh, bh,
                                         out, hbuf, zbuf, rbuf, bar);
}

// Round 2
// 120715.259 us; speedup vs baseline: 1.0212x; 1.0212x over previous
//
#include <hip/hip_runtime.h>

#define BB 128
#define TT 1024
#define II 256
#define HH 512
#define KK 768          // I+H

#define NWG 256         // 1 per CU
#define NTHR 512        // 8 waves/CU
#define WSTRIDE 772     // 768 + 4 pad floats -> conflict-free col-broadcast reads

// Monotonic global barrier (device-scope acq_rel atomics emit the cross-XCD
// L2 writeback/invalidate per the gfx9xx memory model; validated in round 1).
__device__ __forceinline__ void gbar(unsigned* cnt, unsigned target) {
    __syncthreads();
    if (threadIdx.x == 0) {
        __hip_atomic_fetch_add(cnt, 1u, __ATOMIC_ACQ_REL, __HIP_MEMORY_SCOPE_AGENT);
        while (__hip_atomic_load(cnt, __ATOMIC_ACQUIRE, __HIP_MEMORY_SCOPE_AGENT) < target) {
            __builtin_amdgcn_s_sleep(1);
        }
    }
    __syncthreads();
}

__global__ __launch_bounds__(NTHR, 1) void gru_persist(
    const float* __restrict__ x,
    const float* __restrict__ Wz, const float* __restrict__ bz,
    const float* __restrict__ Wr, const float* __restrict__ br,
    const float* __restrict__ Wh, const float* __restrict__ bh,
    float* __restrict__ out,
    float* __restrict__ hbuf,    // [2][B][H]
    float* __restrict__ zbuf,    // [B][H]
    float* __restrict__ rbuf,    // [B][H]
    unsigned* __restrict__ bar)
{
    __shared__ float WA[16 * WSTRIDE];   // 16 cols of [Wz|Wr], col-major, padded
    __shared__ float WB[8 * WSTRIDE];    // 8 cols of Wh
    __shared__ float RED[32 * 8];        // phase-B k-split reduction

    const int wg  = blockIdx.x;
    const int tid = threadIdx.x;
    const int rb  = wg & 3;              // rowblock: constant per XCD (wg%8 -> XCD)
    const int cb  = wg >> 2;             // colblock 0..63
    const int m0  = rb * 32;
    const int nA0 = cb * 16;             // cols in [z|r] space (0..1023), no z/r straddle
    const int nB0 = cb * 8;              // cols in hc space (0..511)

    // ---- one-time weight preload into LDS (k-major index for coalescing) ----
    for (int idx = tid; idx < 16 * KK; idx += NTHR) {
        const int cg = idx & 15, k = idx >> 4;
        const int n = nA0 + cg;
        WA[cg * WSTRIDE + k] = (n < HH) ? Wz[k * HH + n] : Wr[k * HH + (n - HH)];
    }
    for (int idx = tid; idx < 8 * KK; idx += NTHR) {
        const int cg = idx & 7, k = idx >> 3;
        WB[cg * WSTRIDE + k] = Wh[k * HH + (nB0 + cg)];
    }
    __syncthreads();

    // phase A thread mapping: tid = [rep:1][cg:4][m4:4]; wave = 4 cols x 16 rows
    const int m4A  = tid & 15;
    const int cgA  = (tid >> 4) & 15;
    const int repA = tid >> 8;
    const int rowA = m0 + repA * 16 + m4A;
    const int nA   = nA0 + cgA;
    const float biasA = (nA < HH) ? bz[nA] : br[nA - HH];

    // phase B thread mapping: tid = [kh:1][rep:1][cg:3][m4:4]; wave = 4 cols x 16 rows
    const int m4B  = tid & 15;
    const int cgB  = (tid >> 4) & 7;
    const int repB = (tid >> 7) & 1;
    const int khB  = tid >> 8;
    const int rowB = m0 + repB * 16 + m4B;
    const int nB   = nB0 + cgB;
    const float biasB = bh[nB];

    unsigned nbar = 0;

    for (int t = 0; t < TT; ++t) {
        const float* __restrict__ hprev = hbuf + (size_t)(t & 1) * (BB * HH);
        float*       __restrict__ hnext = hbuf + (size_t)((t & 1) ^ 1) * (BB * HH);

        // ---------- phase A: [z|r] = sigmoid([x_t, h] @ [Wz|Wr] + b) ----------
        {
            const float* __restrict__ xr = x + (size_t)rowA * (TT * II) + (size_t)t * II;
            const float* __restrict__ hr = hprev + rowA * HH;
            const float* __restrict__ wa = WA + cgA * WSTRIDE;
            float a0 = 0.f, a1 = 0.f, a2 = 0.f, a3 = 0.f;
            #pragma unroll 8
            for (int k = 0; k < II; k += 4) {
                const float4 c = *(const float4*)(xr + k);
                const float4 w = *(const float4*)(wa + k);
                a0 += c.x * w.x; a1 += c.y * w.y; a2 += c.z * w.z; a3 += c.w * w.w;
            }
            #pragma unroll 8
            for (int k = 0; k < HH; k += 4) {
                const float4 c = *(const float4*)(hr + k);
                const float4 w = *(const float4*)(wa + II + k);
                a0 += c.x * w.x; a1 += c.y * w.y; a2 += c.z * w.z; a3 += c.w * w.w;
            }
            const float v = (a0 + a1) + (a2 + a3) + biasA;
            const float s = 1.f / (1.f + expf(-v));
            if (nA < HH) zbuf[rowA * HH + nA]        = s;
            else         rbuf[rowA * HH + (nA - HH)] = s;
        }
        ++nbar; gbar(bar, nbar * NWG);

        // ---------- phase B: hc = tanh([x_t, r*h] @ Wh + bh); h = (1-z)h + z*hc ----------
        {
            const float* __restrict__ xr = x + (size_t)rowB * (TT * II) + (size_t)t * II;
            const float* __restrict__ hr = hprev + rowB * HH;
            const float* __restrict__ rr = rbuf + rowB * HH;
            const float* __restrict__ wb = WB + cgB * WSTRIDE;
            float a0 = 0.f, a1 = 0.f, a2 = 0.f, a3 = 0.f;
            if (khB == 0) {
                // global k in [0, 384): x-part [0,256) + (r*h)-part [0,128)
                #pragma unroll 8
                for (int k = 0; k < II; k += 4) {
                    const float4 c = *(const float4*)(xr + k);
                    const float4 w = *(const float4*)(wb + k);
                    a0 += c.x * w.x; a1 += c.y * w.y; a2 += c.z * w.z; a3 += c.w * w.w;
                }
                #pragma unroll 8
                for (int k = 0; k < 128; k += 4) {
                    const float4 rv = *(const float4*)(rr + k);
                    const float4 hv = *(const float4*)(hr + k);
                    const float4 w  = *(const float4*)(wb + II + k);
                    a0 += rv.x * hv.x * w.x; a1 += rv.y * hv.y * w.y;
                    a2 += rv.z * hv.z * w.z; a3 += rv.w * hv.w * w.w;
                }
            } else {
                // global k in [384, 768): (r*h)-part [128,512)
                #pragma unroll 8
                for (int k = 128; k < HH; k += 4) {
                    const float4 rv = *(const float4*)(rr + k);
                    const float4 hv = *(const float4*)(hr + k);
                    const float4 w  = *(const float4*)(wb + II + k);
                    a0 += rv.x * hv.x * w.x; a1 += rv.y * hv.y * w.y;
                    a2 += rv.z * hv.z * w.z; a3 += rv.w * hv.w * w.w;
                }
            }
            float v = (a0 + a1) + (a2 + a3);
            const int ridx = (repB * 16 + m4B) * 8 + cgB;
            if (khB == 1) RED[ridx] = v;
            __syncthreads();
            if (khB == 0) {
                v += RED[ridx];
                const float hc = tanhf(v + biasB);
                const float zv = zbuf[rowB * HH + nB];
                const float ho = hr[nB];
                const float hn = (1.f - zv) * ho + zv * hc;
                hnext[rowB * HH + nB] = hn;
                out[(size_t)rowB * (TT * HH) + (size_t)t * HH + nB] = hn;
            }
        }
        ++nbar; gbar(bar, nbar * NWG);
    }
}

extern "C" void kernel_launch(void* const* d_in, const int* in_sizes, int n_in,
                              void* d_out, int out_size, void* d_ws, size_t ws_size,
                              hipStream_t stream) {
    const float* x  = (const float*)d_in[0];
    const float* Wz = (const float*)d_in[1];
    const float* bz = (const float*)d_in[2];
    const float* Wr = (const float*)d_in[3];
    const float* br = (const float*)d_in[4];
    const float* Wh = (const float*)d_in[5];
    const float* bh = (const float*)d_in[6];
    float* out = (float*)d_out;

    float* ws_f  = (float*)d_ws;
    float* hbuf  = ws_f;                        // 2*B*H
    float* zbuf  = hbuf + 2 * BB * HH;          // B*H
    float* rbuf  = zbuf + BB * HH;              // B*H
    unsigned* bar = (unsigned*)(rbuf + BB * HH);

    const size_t need = (size_t)(4 * BB * HH) * sizeof(float) + 64;
    if (ws_size < need) return;

    hipMemsetAsync(hbuf, 0, (size_t)(2 * BB * HH) * sizeof(float), stream);
    hipMemsetAsync(bar, 0, 2 * sizeof(unsigned), stream);

    gru_persist<<<NWG, NTHR, 0, stream>>>(x, Wz, bz, Wr, br, Wh, bh,
                                          out, hbuf, zbuf, rbuf, bar);
}

// Round 3
// 43878.244 us; speedup vs baseline: 2.8095x; 2.7511x over previous
//
#include <hip/hip_runtime.h>
#include <math.h>

#define BB 128
#define TT 1024
#define II 256
#define HH 512
#define KK 768          // I+H

#define NWG 64          // 2 batch rows per WG; 8 WGs per XCD
#define NTHR 512        // 8 waves

// Barrier-free GRU: each WG owns 2 batch rows and the FULL hidden state for
// those rows (h lives in LDS across all 1024 steps). Weights are re-streamed
// from L2/L3 every step. No global sync, no workspace.
__global__ __launch_bounds__(NTHR, 1) void gru_rowsplit(
    const float* __restrict__ x,
    const float* __restrict__ Wz, const float* __restrict__ bz,
    const float* __restrict__ Wr, const float* __restrict__ br,
    const float* __restrict__ Wh, const float* __restrict__ bh,
    float* __restrict__ out)
{
    // [k][row] interleave -> one ds_read_b64 broadcast serves both rows
    __shared__ float comb_i [KK][2];   // k<II: x_t           ; k>=II: h      (persistent)
    __shared__ float comb2_i[KK][2];   // k<II: x_t (copy)    ; k>=II: r*h
    __shared__ float z_s[2][HH];
    __shared__ float red1[8][257];     // pass1 kh=1 partials: [r*4+j][t1], padded
    __shared__ float red2[24][129];    // pass2 kq>0 partials: [(kq-1)*8+r*4+j][t2]

    const int tid  = threadIdx.x;
    const int row0 = blockIdx.x * 2;

    // ---- pass1 mapping: tid = [kh:1][t1:8]; cols 4*t1..4*t1+3 of [z|r] ----
    const int kh = tid >> 8;           // K half: [0,384) or [384,768)
    const int t1 = tid & 255;
    const int n1 = t1 * 4;             // 4-col group never straddles z/r boundary
    const float* __restrict__ w1 =
        ((n1 < HH) ? (Wz + n1) : (Wr + (n1 - HH))) + (size_t)(kh * 384) * HH;

    // ---- pass2 mapping: tid = [kq:2][t2:7]; cols 4*t2..4*t2+3 of hc ----
    const int kq = tid >> 7;           // K quarter of 192
    const int t2 = tid & 127;
    const int n2 = t2 * 4;
    const float* __restrict__ w2 = Wh + n2 + (size_t)(kq * 192) * HH;

    float b1[4], b2[4];
    #pragma unroll
    for (int j = 0; j < 4; ++j) {
        b1[j] = (n1 + j < HH) ? bz[n1 + j] : br[n1 + j - HH];
        b2[j] = bh[n2 + j];
    }

    // h0 = 0
    for (int idx = tid; idx < HH * 2; idx += NTHR)
        comb_i[II + (idx >> 1)][idx & 1] = 0.f;
    __syncthreads();

    for (int t = 0; t < TT; ++t) {
        // ---- S0: stage x_t for both rows ----
        {
            const int r = tid >> 8, k = tid & 255;
            const float v = x[(size_t)(row0 + r) * (TT * II) + (size_t)t * II + k];
            comb_i [k][r] = v;
            comb2_i[k][r] = v;
        }
        __syncthreads();

        // ---- S1: pass1 partial: acc[r][j] over k in [kh*384, kh*384+384) ----
        float a00 = 0.f, a01 = 0.f, a02 = 0.f, a03 = 0.f;
        float a10 = 0.f, a11 = 0.f, a12 = 0.f, a13 = 0.f;
        {
            const int kb = kh * 384;
            #pragma unroll 8
            for (int k = 0; k < 384; ++k) {
                const float4 w = *(const float4*)(w1 + (size_t)k * HH);
                const float2 a = *(const float2*)&comb_i[kb + k][0];
                a00 += a.x * w.x; a01 += a.x * w.y; a02 += a.x * w.z; a03 += a.x * w.w;
                a10 += a.y * w.x; a11 += a.y * w.y; a12 += a.y * w.z; a13 += a.y * w.w;
            }
        }
        if (kh == 1) {
            red1[0][t1] = a00; red1[1][t1] = a01; red1[2][t1] = a02; red1[3][t1] = a03;
            red1[4][t1] = a10; red1[5][t1] = a11; red1[6][t1] = a12; red1[7][t1] = a13;
        }
        __syncthreads();

        // ---- S2: finalize z, r (kh==0 threads); publish z and r*h ----
        if (kh == 0) {
            float acc[2][4] = {{a00, a01, a02, a03}, {a10, a11, a12, a13}};
            #pragma unroll
            for (int r = 0; r < 2; ++r) {
                #pragma unroll
                for (int j = 0; j < 4; ++j) {
                    const int n = n1 + j;
                    const float v = acc[r][j] + red1[r * 4 + j][t1] + b1[j];
                    const float s = 1.f / (1.f + __expf(-v));
                    if (n < HH) {
                        z_s[r][n] = s;
                    } else {
                        const int nh = n - HH;
                        comb2_i[II + nh][r] = s * comb_i[II + nh][r];
                    }
                }
            }
        }
        __syncthreads();

        // ---- S3: pass2 partial: hc accumulation over k in [kq*192, +192) ----
        float c00 = 0.f, c01 = 0.f, c02 = 0.f, c03 = 0.f;
        float c10 = 0.f, c11 = 0.f, c12 = 0.f, c13 = 0.f;
        {
            const int kb = kq * 192;
            #pragma unroll 8
            for (int k = 0; k < 192; ++k) {
                const float4 w = *(const float4*)(w2 + (size_t)k * HH);
                const float2 a = *(const float2*)&comb2_i[kb + k][0];
                c00 += a.x * w.x; c01 += a.x * w.y; c02 += a.x * w.z; c03 += a.x * w.w;
                c10 += a.y * w.x; c11 += a.y * w.y; c12 += a.y * w.z; c13 += a.y * w.w;
            }
        }
        if (kq > 0) {
            const int base = (kq - 1) * 8;
            red2[base + 0][t2] = c00; red2[base + 1][t2] = c01;
            red2[base + 2][t2] = c02; red2[base + 3][t2] = c03;
            red2[base + 4][t2] = c10; red2[base + 5][t2] = c11;
            red2[base + 6][t2] = c12; red2[base + 7][t2] = c13;
        }
        __syncthreads();

        // ---- S4: finalize h (kq==0 threads), write out ----
        if (kq == 0) {
            float acc[2][4] = {{c00, c01, c02, c03}, {c10, c11, c12, c13}};
            #pragma unroll
            for (int r = 0; r < 2; ++r) {
                float hn4[4];
                #pragma unroll
                for (int j = 0; j < 4; ++j) {
                    const int n  = n2 + j;
                    const int jj = r * 4 + j;
                    const float v = acc[r][j] + red2[jj][t2] + red2[8 + jj][t2]
                                  + red2[16 + jj][t2] + b2[j];
                    const float hc = tanhf(v);
                    const float zv = z_s[r][n];
                    const float ho = comb_i[II + n][r];
                    const float hn = (1.f - zv) * ho + zv * hc;
                    comb_i[II + n][r] = hn;
                    hn4[j] = hn;
                }
                *(float4*)&out[(size_t)(row0 + r) * (TT * HH) + (size_t)t * HH + n2] =
                    make_float4(hn4[0], hn4[1], hn4[2], hn4[3]);
            }
        }
        __syncthreads();
    }
}

extern "C" void kernel_launch(void* const* d_in, const int* in_sizes, int n_in,
                              void* d_out, int out_size, void* d_ws, size_t ws_size,
                              hipStream_t stream) {
    const float* x  = (const float*)d_in[0];
    const float* Wz = (const float*)d_in[1];
    const float* bz = (const float*)d_in[2];
    const float* Wr = (const float*)d_in[3];
    const float* br = (const float*)d_in[4];
    const float* Wh = (const float*)d_in[5];
    const float* bh = (const float*)d_in[6];
    float* out = (float*)d_out;

    gru_rowsplit<<<NWG, NTHR, 0, stream>>>(x, Wz, bz, Wr, br, Wh, bh, out);
}

// Round 4
// 13408.424 us; speedup vs baseline: 9.1939x; 3.2724x over previous
//
#include <hip/hip_runtime.h>
#include <math.h>

#define BB 128
#define TT 1024
#define II 256
#define HH 512
#define KK 768

typedef __attribute__((ext_vector_type(8))) short short8v;
typedef __attribute__((ext_vector_type(4))) float float4v;

// ---- workspace layout ----
#define BARS_OFF   0
#define WFRAG_OFF  4096
#define WFRAG_SZ   (96 * 24 * 64 * 16)          // 2,359,296 B bf16 B-fragments
#define GS_OFF     (WFRAG_OFF + WFRAG_SZ)
#define GS_STRIDE  131072                        // per-group state blob
#define GS_RHF     32768
#define GS_HFP     65536
#define GS_ZFP     98304
#define WS_NEED    ((size_t)GS_OFF + 8 * GS_STRIDE)

__device__ __forceinline__ unsigned short bf16_rne(float f) {
    unsigned u = __builtin_bit_cast(unsigned, f);
    unsigned r = u + 0x7FFFu + ((u >> 16) & 1u);
    return (unsigned short)(r >> 16);
}
__device__ __forceinline__ float bf16_tof(unsigned short h) {
    unsigned u = ((unsigned)h) << 16;
    return __builtin_bit_cast(float, u);
}
__device__ __forceinline__ void cp16(void* lds, const void* g) {
    __builtin_amdgcn_global_load_lds(
        (const __attribute__((address_space(1))) unsigned*)g,
        (__attribute__((address_space(3))) unsigned*)lds, 16, 0, 0);
}
__device__ __forceinline__ void bar_arrive(unsigned* c) {
    __hip_atomic_fetch_add(c, 1u, __ATOMIC_RELEASE, __HIP_MEMORY_SCOPE_AGENT);
}
__device__ __forceinline__ void bar_wait(unsigned* c, unsigned tgt) {
    while (__hip_atomic_load(c, __ATOMIC_RELAXED, __HIP_MEMORY_SCOPE_AGENT) < tgt)
        __builtin_amdgcn_s_sleep(2);
    __builtin_amdgcn_fence(__ATOMIC_ACQUIRE, "agent");
}

#define MFMA __builtin_amdgcn_mfma_f32_16x16x32_bf16

// ---- one-time weight repack: fp32 [768][512] -> bf16 MFMA B-fragments ----
// frag(ntAll, kt): lane l, elem j -> W[kt*32 + (l>>4)*8 + j][n0 + (l&15)]
// ntAll 0..31: Wz, 32..63: Wr, 64..95: Wh
__global__ void repack_w(const float* __restrict__ Wz, const float* __restrict__ Wr,
                         const float* __restrict__ Wh, short8v* __restrict__ wB) {
    const int ntAll = blockIdx.x;
    const int w = threadIdx.x >> 6, l = threadIdx.x & 63;
    const float* W; int n0;
    if (ntAll < 32)      { W = Wz; n0 = ntAll * 16; }
    else if (ntAll < 64) { W = Wr; n0 = (ntAll - 32) * 16; }
    else                 { W = Wh; n0 = (ntAll - 64) * 16; }
    const int n = n0 + (l & 15);
    for (int kt = w; kt < 24; kt += 4) {
        const int k0 = kt * 32 + (l >> 4) * 8;
        short8v f;
        #pragma unroll
        for (int j = 0; j < 8; ++j)
            f[j] = (short)bf16_rne(W[(size_t)(k0 + j) * HH + n]);
        wB[((size_t)ntAll * 24 + kt) * 64 + l] = f;
    }
}

// ---- persistent MFMA GRU ----
// 128 WGs x 256 thr. group g = bid&7 (16 batch rows), slice s = bid>>3 (0..15).
// P1: wave wi = s*4+w computes one 16-col tile of [z|r] (wi<32: z, else r).
// P2: waves (w&1 -> n-tile of hc, w>>1 -> K-half), LDS-reduce, blend.
// Weights LDS-resident (144 KB); h / r*h cross WG via bf16 hi/lo A-fragments
// in per-group global buffers, ordered by 16-WG monotonic barriers.
__global__ __launch_bounds__(256, 1) void gru_mfma(
    const float* __restrict__ x,
    const float* __restrict__ bz, const float* __restrict__ br,
    const float* __restrict__ bh,
    float* __restrict__ out,
    const short8v* __restrict__ wB,
    char* __restrict__ gsBase,
    unsigned* __restrict__ bars)
{
    __shared__ short8v bP1[4][24][64];   // 96 KB: per-wave P1 B strips
    __shared__ short8v bP2[2][24][64];   // 48 KB: P2 B strips
    __shared__ short8v xF[8][64];        //  8 KB: x_t A-fragments (bf16)
    __shared__ float   shpad[1024];      //  4 KB: red[0..511], hStage[512..1023]; rhStage P1

    const int tid = threadIdx.x;
    const int w = tid >> 6, l = tid & 63;
    const int g = blockIdx.x & 7, s = blockIdx.x >> 3;
    const int m_ = l & 15, kg = l >> 4;

    char* gs = gsBase + (size_t)g * GS_STRIDE;
    short8v* hF  = (short8v*)gs;                 // h A-frags  [kt16][hl2][64]
    short8v* rhF = (short8v*)(gs + GS_RHF);      // r*h A-frags
    float*   hFP = (float*)(gs + GS_HFP);        // h fp32 [16][512]
    float*   zFP = (float*)(gs + GS_ZFP);        // z fp32 [16][512]
    unsigned* bar = bars + g * 32;

    const int wi = s * 4 + w;
    const bool isZ = (wi < 32);
    const int colg1 = (isZ ? wi : wi - 32) * 16 + m_;
    const float bias1 = isZ ? bz[colg1] : br[colg1];
    const int ntP2 = w & 1, kh = w >> 1;
    const int colg2 = (s * 2 + ntP2) * 16 + m_;
    const float bias2 = bh[colg2];
    const bool isRWG = (s >= 8);

    const short8v* wP1 = wB + (size_t)wi * 24 * 64;
    const short8v* wP2 = wB + (size_t)(64 + s * 2 + ntP2) * 24 * 64;

    // one-time weight prefetch into LDS (stays resident for all 1024 steps)
    for (int kt = 0; kt < 24; ++kt)
        cp16(&bP1[w][kt][0], wP1 + kt * 64 + l);
    {
        const int k0 = kh * 12;
        for (int i = 0; i < 12; ++i)
            cp16(&bP2[ntP2][k0 + i][0], wP2 + (k0 + i) * 64 + l);
    }

    unsigned tgt = 0;

    for (int t = 0; t < TT; ++t) {
        // ---- stage x_t fragments (single bf16) ----
        for (int slot = tid; slot < 512; slot += 256) {
            const int kt = slot >> 6, ll = slot & 63;
            const float* xp = x + (size_t)(g * 16 + (ll & 15)) * (TT * II)
                                + (size_t)t * II + kt * 32 + (ll >> 4) * 8;
            const float4 v0 = *(const float4*)xp;
            const float4 v1 = *(const float4*)(xp + 4);
            short8v f;
            f[0] = (short)bf16_rne(v0.x); f[1] = (short)bf16_rne(v0.y);
            f[2] = (short)bf16_rne(v0.z); f[3] = (short)bf16_rne(v0.w);
            f[4] = (short)bf16_rne(v1.x); f[5] = (short)bf16_rne(v1.y);
            f[6] = (short)bf16_rne(v1.z); f[7] = (short)bf16_rne(v1.w);
            xF[kt][ll] = f;
        }
        __syncthreads();   // xF ready; also drains prologue vmcnt on first iter

        // ---- P1: [z|r] = sigmoid([x,h] @ [Wz|Wr] + b) ----
        float4v a0 = {0.f,0.f,0.f,0.f}, a1 = a0, a2 = a0, a3 = a0;
        #pragma unroll
        for (int kt = 0; kt < 8; ++kt) {
            const short8v av = xF[kt][l];
            const short8v bv = bP1[w][kt][l];
            switch (kt & 3) {
                case 0: a0 = MFMA(av, bv, a0, 0, 0, 0); break;
                case 1: a1 = MFMA(av, bv, a1, 0, 0, 0); break;
                case 2: a2 = MFMA(av, bv, a2, 0, 0, 0); break;
                default: a3 = MFMA(av, bv, a3, 0, 0, 0); break;
            }
        }
        #pragma unroll
        for (int kt = 0; kt < 16; ++kt) {
            const short8v bv = bP1[w][8 + kt][l];
            const short8v ah = hF[(kt * 2 + 0) * 64 + l];
            const short8v al = hF[(kt * 2 + 1) * 64 + l];
            switch (kt & 3) {
                case 0: a0 = MFMA(ah, bv, a0, 0, 0, 0); a0 = MFMA(al, bv, a0, 0, 0, 0); break;
                case 1: a1 = MFMA(ah, bv, a1, 0, 0, 0); a1 = MFMA(al, bv, a1, 0, 0, 0); break;
                case 2: a2 = MFMA(ah, bv, a2, 0, 0, 0); a2 = MFMA(al, bv, a2, 0, 0, 0); break;
                default: a3 = MFMA(ah, bv, a3, 0, 0, 0); a3 = MFMA(al, bv, a3, 0, 0, 0); break;
            }
        }
        float4v acc;
        acc[0] = a0[0] + a1[0] + a2[0] + a3[0];
        acc[1] = a0[1] + a1[1] + a2[1] + a3[1];
        acc[2] = a0[2] + a1[2] + a2[2] + a3[2];
        acc[3] = a0[3] + a1[3] + a2[3] + a3[3];
        #pragma unroll
        for (int r = 0; r < 4; ++r) {
            const int row = kg * 4 + r;
            const float v = acc[r] + bias1;
            const float sg = 1.f / (1.f + __expf(-v));
            if (isZ) {
                zFP[row * HH + colg1] = sg;
            } else {
                const float ho = hFP[row * HH + colg1];
                shpad[w * 256 + row * 16 + m_] = sg * ho;   // r*h staging
            }
        }
        if (isRWG) {
            __syncthreads();
            if (tid < 128) {   // pack r*h -> hi/lo A-fragments (2 k-tiles/WG)
                const int ktl = tid >> 6, ll = tid & 63;
                const int mm = ll & 15, kgg = ll >> 4;
                const int wsrc = ktl * 2 + (kgg >> 1), cb = (kgg & 1) * 8;
                short8v hi8, lo8;
                #pragma unroll
                for (int j = 0; j < 8; ++j) {
                    const float v = shpad[wsrc * 256 + mm * 16 + cb + j];
                    const unsigned short h = bf16_rne(v);
                    hi8[j] = (short)h;
                    lo8[j] = (short)bf16_rne(v - bf16_tof(h));
                }
                const int ktg = (s - 8) * 2 + ktl;
                rhF[(ktg * 2 + 0) * 64 + ll] = hi8;
                rhF[(ktg * 2 + 1) * 64 + ll] = lo8;
            }
        }
        __syncthreads();
        ++tgt;
        if (tid == 0) { bar_arrive(bar); bar_wait(bar, tgt * 16); }
        __syncthreads();

        // ---- P2: hc = tanh([x, r*h] @ Wh + b); h = (1-z)h + z*hc ----
        float4v b0 = {0.f,0.f,0.f,0.f}, b1 = b0;
        if (kh == 0) {
            #pragma unroll
            for (int kt = 0; kt < 8; ++kt) {
                const short8v av = xF[kt][l];
                const short8v bv = bP2[ntP2][kt][l];
                if (kt & 1) b1 = MFMA(av, bv, b1, 0, 0, 0);
                else        b0 = MFMA(av, bv, b0, 0, 0, 0);
            }
            #pragma unroll
            for (int kt = 8; kt < 12; ++kt) {
                const short8v bv = bP2[ntP2][kt][l];
                const short8v ah = rhF[((kt - 8) * 2 + 0) * 64 + l];
                const short8v al = rhF[((kt - 8) * 2 + 1) * 64 + l];
                if (kt & 1) { b1 = MFMA(ah, bv, b1, 0, 0, 0); b1 = MFMA(al, bv, b1, 0, 0, 0); }
                else        { b0 = MFMA(ah, bv, b0, 0, 0, 0); b0 = MFMA(al, bv, b0, 0, 0, 0); }
            }
        } else {
            #pragma unroll
            for (int kt = 12; kt < 24; ++kt) {
                const short8v bv = bP2[ntP2][kt][l];
                const short8v ah = rhF[((kt - 8) * 2 + 0) * 64 + l];
                const short8v al = rhF[((kt - 8) * 2 + 1) * 64 + l];
                if (kt & 1) { b1 = MFMA(ah, bv, b1, 0, 0, 0); b1 = MFMA(al, bv, b1, 0, 0, 0); }
                else        { b0 = MFMA(ah, bv, b0, 0, 0, 0); b0 = MFMA(al, bv, b0, 0, 0, 0); }
            }
        }
        acc[0] = b0[0] + b1[0]; acc[1] = b0[1] + b1[1];
        acc[2] = b0[2] + b1[2]; acc[3] = b0[3] + b1[3];
        if (kh == 1) {
            #pragma unroll
            for (int r = 0; r < 4; ++r)
                shpad[ntP2 * 256 + (kg * 4 + r) * 16 + m_] = acc[r];
        }
        __syncthreads();
        if (kh == 0) {
            #pragma unroll
            for (int r = 0; r < 4; ++r) {
                const int row = kg * 4 + r;
                const float v = acc[r] + shpad[ntP2 * 256 + row * 16 + m_] + bias2;
                const float hc = tanhf(v);
                const float zv = zFP[row * HH + colg2];
                const float ho = hFP[row * HH + colg2];
                const float hn = (1.f - zv) * ho + zv * hc;
                hFP[row * HH + colg2] = hn;
                out[(size_t)(g * 16 + row) * (TT * HH) + (size_t)t * HH + colg2] = hn;
                shpad[512 + row * 32 + ntP2 * 16 + m_] = hn;
            }
        }
        __syncthreads();
        if (tid < 64) {   // pack h_new -> hi/lo A-fragments (1 k-tile/WG: kt=s)
            const int mm = tid & 15, kgg = tid >> 4;
            short8v hi8, lo8;
            #pragma unroll
            for (int j = 0; j < 8; ++j) {
                const float v = shpad[512 + mm * 32 + kgg * 8 + j];
                const unsigned short h = bf16_rne(v);
                hi8[j] = (short)h;
                lo8[j] = (short)bf16_rne(v - bf16_tof(h));
            }
            hF[(s * 2 + 0) * 64 + tid] = hi8;
            hF[(s * 2 + 1) * 64 + tid] = lo8;
        }
        ++tgt;
        if (tid == 0) { bar_arrive(bar); bar_wait(bar, tgt * 16); }
        __syncthreads();
    }
}

// ---------------- fallback (round-3 kernel) if ws too small ----------------
#define NWG_FB 64
#define NTHR_FB 512
__global__ __launch_bounds__(NTHR_FB, 1) void gru_rowsplit(
    const float* __restrict__ x,
    const float* __restrict__ Wz, const float* __restrict__ bz,
    const float* __restrict__ Wr, const float* __restrict__ br,
    const float* __restrict__ Wh, const float* __restrict__ bh,
    float* __restrict__ out)
{
    __shared__ float comb_i [KK][2];
    __shared__ float comb2_i[KK][2];
    __shared__ float z_s[2][HH];
    __shared__ float red1[8][257];
    __shared__ float red2[24][129];

    const int tid  = threadIdx.x;
    const int row0 = blockIdx.x * 2;
    const int kh = tid >> 8;
    const int t1 = tid & 255;
    const int n1 = t1 * 4;
    const float* __restrict__ w1 =
        ((n1 < HH) ? (Wz + n1) : (Wr + (n1 - HH))) + (size_t)(kh * 384) * HH;
    const int kq = tid >> 7;
    const int t2 = tid & 127;
    const int n2 = t2 * 4;
    const float* __restrict__ w2 = Wh + n2 + (size_t)(kq * 192) * HH;

    float b1[4], b2[4];
    #pragma unroll
    for (int j = 0; j < 4; ++j) {
        b1[j] = (n1 + j < HH) ? bz[n1 + j] : br[n1 + j - HH];
        b2[j] = bh[n2 + j];
    }
    for (int idx = tid; idx < HH * 2; idx += NTHR_FB)
        comb_i[II + (idx >> 1)][idx & 1] = 0.f;
    __syncthreads();

    for (int t = 0; t < TT; ++t) {
        {
            const int r = tid >> 8, k = tid & 255;
            const float v = x[(size_t)(row0 + r) * (TT * II) + (size_t)t * II + k];
            comb_i [k][r] = v;
            comb2_i[k][r] = v;
        }
        __syncthreads();
        float a00=0,a01=0,a02=0,a03=0,a10=0,a11=0,a12=0,a13=0;
        {
            const int kb = kh * 384;
            #pragma unroll 8
            for (int k = 0; k < 384; ++k) {
                const float4 w = *(const float4*)(w1 + (size_t)k * HH);
                const float2 a = *(const float2*)&comb_i[kb + k][0];
                a00 += a.x*w.x; a01 += a.x*w.y; a02 += a.x*w.z; a03 += a.x*w.w;
                a10 += a.y*w.x; a11 += a.y*w.y; a12 += a.y*w.z; a13 += a.y*w.w;
            }
        }
        if (kh == 1) {
            red1[0][t1]=a00; red1[1][t1]=a01; red1[2][t1]=a02; red1[3][t1]=a03;
            red1[4][t1]=a10; red1[5][t1]=a11; red1[6][t1]=a12; red1[7][t1]=a13;
        }
        __syncthreads();
        if (kh == 0) {
            float accv[2][4] = {{a00,a01,a02,a03},{a10,a11,a12,a13}};
            #pragma unroll
            for (int r = 0; r < 2; ++r) {
                #pragma unroll
                for (int j = 0; j < 4; ++j) {
                    const int n = n1 + j;
                    const float v = accv[r][j] + red1[r*4+j][t1] + b1[j];
                    const float sg = 1.f / (1.f + __expf(-v));
                    if (n < HH) z_s[r][n] = sg;
                    else {
                        const int nh = n - HH;
                        comb2_i[II + nh][r] = sg * comb_i[II + nh][r];
                    }
                }
            }
        }
        __syncthreads();
        float c00=0,c01=0,c02=0,c03=0,c10=0,c11=0,c12=0,c13=0;
        {
            const int kb = kq * 192;
            #pragma unroll 8
            for (int k = 0; k < 192; ++k) {
                const float4 w = *(const float4*)(w2 + (size_t)k * HH);
                const float2 a = *(const float2*)&comb2_i[kb + k][0];
                c00 += a.x*w.x; c01 += a.x*w.y; c02 += a.x*w.z; c03 += a.x*w.w;
                c10 += a.y*w.x; c11 += a.y*w.y; c12 += a.y*w.z; c13 += a.y*w.w;
            }
        }
        if (kq > 0) {
            const int base = (kq - 1) * 8;
            red2[base+0][t2]=c00; red2[base+1][t2]=c01;
            red2[base+2][t2]=c02; red2[base+3][t2]=c03;
            red2[base+4][t2]=c10; red2[base+5][t2]=c11;
            red2[base+6][t2]=c12; red2[base+7][t2]=c13;
        }
        __syncthreads();
        if (kq == 0) {
            float accv[2][4] = {{c00,c01,c02,c03},{c10,c11,c12,c13}};
            #pragma unroll
            for (int r = 0; r < 2; ++r) {
                float hn4[4];
                #pragma unroll
                for (int j = 0; j < 4; ++j) {
                    const int n = n2 + j;
                    const int jj = r * 4 + j;
                    const float v = accv[r][j] + red2[jj][t2] + red2[8+jj][t2]
                                  + red2[16+jj][t2] + b2[j];
                    const float hc = tanhf(v);
                    const float zv = z_s[r][n];
                    const float ho = comb_i[II + n][r];
                    const float hn = (1.f - zv) * ho + zv * hc;
                    comb_i[II + n][r] = hn;
                    hn4[j] = hn;
                }
                *(float4*)&out[(size_t)(row0 + r) * (TT * HH) + (size_t)t * HH + n2] =
                    make_float4(hn4[0], hn4[1], hn4[2], hn4[3]);
            }
        }
        __syncthreads();
    }
}

extern "C" void kernel_launch(void* const* d_in, const int* in_sizes, int n_in,
                              void* d_out, int out_size, void* d_ws, size_t ws_size,
                              hipStream_t stream) {
    const float* x  = (const float*)d_in[0];
    const float* Wz = (const float*)d_in[1];
    const float* bz = (const float*)d_in[2];
    const float* Wr = (const float*)d_in[3];
    const float* br = (const float*)d_in[4];
    const float* Wh = (const float*)d_in[5];
    const float* bh = (const float*)d_in[6];
    float* out = (float*)d_out;

    if (ws_size < WS_NEED) {
        gru_rowsplit<<<NWG_FB, NTHR_FB, 0, stream>>>(x, Wz, bz, Wr, br, Wh, bh, out);
        return;
    }

    char* ws = (char*)d_ws;
    unsigned* bars = (unsigned*)(ws + BARS_OFF);
    short8v*  wB   = (short8v*)(ws + WFRAG_OFF);
    char*     gs   = ws + GS_OFF;

    hipMemsetAsync(bars, 0, 4096, stream);
    hipMemsetAsync(gs, 0, 8 * (size_t)GS_STRIDE, stream);   // zero h, frags, z
    repack_w<<<96, 256, 0, stream>>>(Wz, Wr, Wh, wB);
    gru_mfma<<<128, 256, 0, stream>>>(x, bz, br, bh, out, wB, gs, bars);
}